// Round 13
// baseline (470.179 us; speedup 1.0000x reference)
//
#include <hip/hip_runtime.h>
#include <hip/hip_cooperative_groups.h>

// Attention_34187939676863 on MI355X (gfx950). fp32 I/O, bf16 MFMA internally.
// B=4, S=2048, D=1024.  Wk unused (reference bug: Wv used for both K and V),
// mask unused (causal structure implemented directly).
//
//   prep  : qb16 = bf16(q); Wqt/Wvt transposes; rowsum = 0   [one kernel]
//   WQ    = qb16 @ Wq,  WKV = qb16 @ Wv      [256x256 8-phase bt-GEMM, XCD-pinned
//                                             m-stripes; z=1 epilogue also emits WKVt]
//   gemm_sp (cooperative, grid 768 = 3/CU): scores phase -> grid.sync -> pv phase
//     P'    = exp(WQ @ WKV^T / 32) causal bf16 [64x128, 2 K-tiles/superstep]
//     rowsum= sum_k P'                          [fused epilogue atomics]
//     out   = (P' @ WKV) / rowsum fp32         [64x128, 2 K-tiles/superstep]
//
// Round-18: r12 confirmed the r8 structure (198.7-204.8 band), but components
// sum to ~130us at fast clock vs ~203 wall -> ~60-70us is inter-dispatch
// boundary cost (AQL barrier + L2 flush per dependency). r11's persistent
// fusion failed because acquire fences were PER-TILE (1024 invalidations
// spread through pv -> FETCH 280MB). This round uses the sanctioned
// mechanism: hipLaunchCooperativeKernel + ONE grid.sync() -- all
// invalidations at the phase boundary (768 at once), then pv's L2 reuse is
// untouched. Static work map preserves the XCD decode verbatim; identical
// tile bodies + K-order -> bit-identical numerics. Runtime fallback to the
// proven separate launches if cooperative launch errors.
// Falsifier: total >= 202 or FETCH ~280MB -> revert to r12 as final.
//
// Workspace (needs ws_size >= 81 MB):
//   [0,2)MB Wqt | [2,4) Wvt | [4,20) qb16   <- dead after proj
//   [0,32) Pp bf16 [B][S][S] (overlays the above)
//   [32,48) WQ | [48,64) WKV | [64,80) WKVt | [80MB,+32KB) rowsum fp32

typedef unsigned short u16;
typedef short short8 __attribute__((ext_vector_type(8)));
typedef float floatx4 __attribute__((ext_vector_type(4)));

#define S_LEN 2048
#define D_DIM 1024
#define BK 64

__device__ inline u16 f2b(float f) {
  unsigned u = __float_as_uint(f);
  return (u16)((u + 0x7fffu + ((u >> 16) & 1u)) >> 16);
}

// async global->LDS, 16B/lane; LDS dest = wave-uniform base + lane*16
__device__ __forceinline__ void gload16(const u16* g, u16* l) {
  __builtin_amdgcn_global_load_lds(
      (const __attribute__((address_space(1))) void*)g,
      (__attribute__((address_space(3))) void*)l, 16, 0, 0);
}

// prep: grid 4608 x 256.
//   id <  4096 : cvt q -> qb16 (8 elems/thread); ids 0..3 also zero rowsum
//   id >= 4096 : 64x64 f32->bf16 transpose tiles of Wq->Wqt (z=0) / Wv->Wvt (z=1)
__global__ __launch_bounds__(256)
void prep(const float* __restrict__ q, u16* __restrict__ qb16,
          const float* __restrict__ Wq, u16* __restrict__ Wqt,
          const float* __restrict__ Wv, u16* __restrict__ Wvt,
          float* __restrict__ rowsum) {
  int id = blockIdx.x, tid = threadIdx.x;
  if (id < 4096) {
    if (id < 4) {
      int o = id * 2048 + tid * 8;
      float4 zz = {0.f, 0.f, 0.f, 0.f};
      *(float4*)&rowsum[o] = zz;
      *(float4*)&rowsum[o + 4] = zz;
    }
    size_t idx = ((size_t)id * 256 + tid) * 8;
    float4 a0 = *(const float4*)&q[idx];
    float4 a1 = *(const float4*)&q[idx + 4];
    short8 v;
    v[0] = (short)f2b(a0.x); v[1] = (short)f2b(a0.y);
    v[2] = (short)f2b(a0.z); v[3] = (short)f2b(a0.w);
    v[4] = (short)f2b(a1.x); v[5] = (short)f2b(a1.y);
    v[6] = (short)f2b(a1.z); v[7] = (short)f2b(a1.w);
    *(short8*)&qb16[idx] = v;
    return;
  }
  __shared__ u16 tile[64][65];
  int id2 = id - 4096;               // 0..511
  int z = id2 >> 8;                  // matrix select
  int idx4 = id2 & 255;
  int c0 = (idx4 & 15) * 64, r0 = (idx4 >> 4) * 64;
  const float* src = z ? Wv : Wq;
  u16* dst = z ? Wvt : Wqt;
  int tx = tid & 63, ty = tid >> 6;
#pragma unroll
  for (int i = 0; i < 16; ++i)
    tile[i * 4 + ty][tx] =
        f2b(src[(size_t)(r0 + i * 4 + ty) * 1024 + (c0 + tx)]);
  __syncthreads();
#pragma unroll
  for (int i = 0; i < 16; ++i)
    dst[(size_t)(c0 + i * 4 + ty) * 1024 + (r0 + tx)] = tile[tx][i * 4 + ty];
}

// Projections: WQ = qb16 @ Wqt^T (z=0), WKV = qb16 @ Wvt^T (z=1; also WKVt).
// 256x256 tile, 8 waves (2m x 4n), 8-phase double-buffered K-loop.
// Grid 256 = 8 XCDs x (4 m-stripes x 8 n-tiles): 1 block/CU exactly.
__global__ __launch_bounds__(512, 2)
void gemm_proj(const u16* __restrict__ A, const u16* __restrict__ B0,
               const u16* __restrict__ B1, u16* __restrict__ C0,
               u16* __restrict__ C1, u16* __restrict__ WKVt) {
  __shared__ __align__(16) u16 lds[65536];  // 128 KiB

  int id = blockIdx.x;
  int xcd = id & 7, i5 = id >> 3;
  int m_idx = xcd * 4 + (i5 & 3);  // XCD owns 4 m-stripes (2MB of A in L2)
  int n_idx = i5 >> 2;             // 0..7
  int z = n_idx >> 2;
  int n0 = (n_idx & 3) * 256;
  int m0 = m_idx * 256;
  const u16* Bp = z ? B1 : B0;
  u16* Cp = z ? C1 : C0;

  int tid = threadIdx.x;
  int wv = tid >> 6, lane = tid & 63, quad = lane >> 4, l15 = lane & 15;
  int wm = wv >> 2, wn = wv & 3;  // wave -> (m-half, n-quarter)

  int off_g[2];
#pragma unroll
  for (int l = 0; l < 2; ++l) {
    int chunk = (wv * 2 + l) * 64 + lane;
    int r = chunk >> 3, cs = chunk & 7;
    off_g[l] = r * 1024 + (cs ^ (r & 7)) * 8;
  }
  const u16* As0 = A + (size_t)m0 * 1024;
  const u16* As1 = A + (size_t)(m0 + 128) * 1024;
  const u16* Bs0 = Bp + (size_t)n0 * 1024;
  const u16* Bs1 = Bp + (size_t)(n0 + 128) * 1024;

#define PSTAGE(src, reg)                                                     \
  {                                                                          \
    _Pragma("unroll") for (int l = 0; l < 2; ++l)                            \
        gload16((src) + off_g[l], &lds[(reg) * 8192 + (wv * 2 + l) * 512]);  \
  }

  int aoff[2], boff[2];
#pragma unroll
  for (int kk = 0; kk < 2; ++kk) {
    int c = ((kk * 4 + quad) ^ (l15 & 7)) * 8;
    aoff[kk] = l15 * 64 + c;
    boff[kk] = ((wn & 1) * 64 + l15) * 64 + c;
  }
  const u16* A0p = &lds[(0 + wm) * 8192];         // buf0 A-half of this wave
  const u16* A1p = &lds[(4 + wm) * 8192];         // buf1 A-half
  const u16* B0p = &lds[(2 + (wn >> 1)) * 8192];  // buf0 B-half
  const u16* B1p = &lds[(6 + (wn >> 1)) * 8192];  // buf1 B-half

  floatx4 acc[8][4];
#pragma unroll
  for (int i = 0; i < 8; ++i)
#pragma unroll
    for (int j = 0; j < 4; ++j) acc[i][j] = (floatx4){0.f, 0.f, 0.f, 0.f};

#define BARp() __builtin_amdgcn_s_barrier()
#define WLG() asm volatile("s_waitcnt lgkmcnt(0)" ::: "memory")
#define WVM(n) asm volatile("s_waitcnt vmcnt(" #n ")" ::: "memory")

#define RDA(dst, base, fb)                                                 \
  _Pragma("unroll") for (int f = 0; f < 4; ++f)                            \
  _Pragma("unroll") for (int kk = 0; kk < 2; ++kk)                         \
      dst[f][kk] = *(const short8*)&(base)[((fb) + f) * 1024 + aoff[kk]];
#define RDB(dst, base, fb)                                                 \
  _Pragma("unroll") for (int f = 0; f < 2; ++f)                            \
  _Pragma("unroll") for (int kk = 0; kk < 2; ++kk)                         \
      dst[f][kk] = *(const short8*)&(base)[((fb) + f) * 1024 + boff[kk]];
#define MMQ(mh, nh, afq, bfq)                                              \
  __builtin_amdgcn_s_setprio(1);                                           \
  _Pragma("unroll") for (int f = 0; f < 4; ++f)                            \
  _Pragma("unroll") for (int g2 = 0; g2 < 2; ++g2)                         \
  _Pragma("unroll") for (int kk = 0; kk < 2; ++kk)                         \
      acc[(mh) * 4 + f][(nh) * 2 + g2] =                                   \
          __builtin_amdgcn_mfma_f32_16x16x32_bf16(                         \
              afq[f][kk], bfq[g2][kk], acc[(mh) * 4 + f][(nh) * 2 + g2],   \
              0, 0, 0);                                                    \
  __builtin_amdgcn_s_setprio(0);

  // Prologue: stage kt0 (regions 0-3) + kt1 (regions 4-7); wait kt0 landed.
  PSTAGE(As0, 0); PSTAGE(As1, 1); PSTAGE(Bs0, 2); PSTAGE(Bs1, 3);
  PSTAGE(As0 + 64, 4); PSTAGE(As1 + 64, 5); PSTAGE(Bs0 + 64, 6);
  PSTAGE(Bs1 + 64, 7);
  WVM(8);
  BARp();

#pragma unroll 1
  for (int it = 0; it < 8; ++it) {
    int kb2 = it * 128 + 128, kb3 = it * 128 + 192;  // kt+2 / kt+3 K-bases
    short8 af[4][2], bf0[2][2], bf1[2][2];
    // ---- K-tile 2it (buf0), phases q0..q3 ----
    RDA(af, A0p, 0); RDB(bf0, B0p, 0);
    BARp(); WLG();
    MMQ(0, 0, af, bf0);
    BARp();
    RDB(bf1, B0p, 2);
    BARp(); WLG();
    MMQ(0, 1, af, bf1);
    BARp();
    RDA(af, A0p, 4);
    if (it < 7) PSTAGE(Bs0 + kb2, 2);
    BARp(); WLG();
    MMQ(1, 1, af, bf1);
    BARp();
    if (it < 7) { PSTAGE(Bs1 + kb2, 3); PSTAGE(As0 + kb2, 0); }
    BARp();
    MMQ(1, 0, af, bf0);
    if (it < 7) { WVM(6); } else { WVM(0); }  // buf1 K-tile landed
    BARp();
    // ---- K-tile 2it+1 (buf1), phases q4..q7 ----
    RDA(af, A1p, 0); RDB(bf0, B1p, 0);
    if (it < 7) PSTAGE(As1 + kb2, 1);
    BARp(); WLG();
    MMQ(0, 0, af, bf0);
    BARp();
    RDB(bf1, B1p, 2);
    BARp(); WLG();
    MMQ(0, 1, af, bf1);
    BARp();
    RDA(af, A1p, 4);
    if (it < 7) PSTAGE(Bs0 + kb3, 6);
    BARp(); WLG();
    MMQ(1, 1, af, bf1);
    BARp();
    if (it < 7) {
      PSTAGE(Bs1 + kb3, 7); PSTAGE(As0 + kb3, 4); PSTAGE(As1 + kb3, 5);
    }
    BARp();
    MMQ(1, 0, af, bf0);
    if (it < 7) WVM(8);  // next buf0 K-tile landed
    BARp();
  }

  asm volatile("s_waitcnt vmcnt(0) lgkmcnt(0)" ::: "memory");
  // C write. C/D layout: col=lane&15, row=quad*4+reg  [m89-verified]
#pragma unroll
  for (int mf = 0; mf < 8; ++mf)
#pragma unroll
    for (int nf = 0; nf < 4; ++nf)
#pragma unroll
      for (int r = 0; r < 4; ++r)
        Cp[(size_t)(m0 + wm * 128 + mf * 16 + quad * 4 + r) * D_DIM +
           (n0 + wn * 64 + nf * 16 + l15)] = f2b(acc[mf][nf][r]);

  if (z) {
    // Fused WKV^T: acc -> LDS transposed (two 128-col passes) -> 16B stores.
    int b = m0 >> 11, srow = m0 & 2047;
    u16* Wt = WKVt + (size_t)b * D_DIM * S_LEN;
#pragma unroll
    for (int ph = 0; ph < 2; ++ph) {
      BARp();  // LDS reusable / previous pass reads done
      if ((wn >> 1) == ph) {
#pragma unroll
        for (int mf = 0; mf < 8; ++mf)
#pragma unroll
          for (int nf = 0; nf < 4; ++nf)
#pragma unroll
            for (int r = 0; r < 4; ++r)
              lds[((wn & 1) * 64 + nf * 16 + l15) * 272 +
                  (wm * 128 + mf * 16 + quad * 4 + r)] = f2b(acc[mf][nf][r]);
      }
      BARp();
#pragma unroll
      for (int rr = 0; rr < 8; ++rr) {
        int idx = rr * 512 + tid;  // 0..4095: (d-local, s-chunk)
        int dl = idx >> 5, sc = idx & 31;
        *(short8*)&Wt[(size_t)(n0 + ph * 128 + dl) * S_LEN + srow + sc * 8] =
            *(const short8*)&lds[dl * 272 + sc * 8];
      }
    }
  }
}

// ---- 64x128-tile bt-GEMM core, 2 K-tiles per superstep (scores/pv) ----
// Als/Bls must be in scope as [2][...] arrays or pointer-to-array.
#define GEMM64_PROLOG()                                                       \
  __shared__ __align__(16) u16 Als[2][64 * BK];                               \
  __shared__ __align__(16) u16 Bls[2][128 * BK];                              \
  int tid = threadIdx.x;                                                      \
  int wave = tid >> 6, lane = tid & 63, quad = lane >> 4, l15 = lane & 15;    \
  int wr = (wave >> 1) * 32, wc = (wave & 1) * 64;                            \
  int arow = lane >> 3;                                                       \
  int acol = ((lane & 7) ^ (arow & 7)) << 3;                                  \
  floatx4 acc[2][4];                                                          \
  _Pragma("unroll") for (int i = 0; i < 2; ++i)                               \
  _Pragma("unroll") for (int j = 0; j < 4; ++j)                               \
      acc[i][j] = (floatx4){0.f, 0.f, 0.f, 0.f};

#define GEMM64_STAGE(buf, Aptr, lda, Bptr, ldb, kb)                           \
  {                                                                           \
    _Pragma("unroll") for (int p = 0; p < 2; ++p) {                           \
      int r0 = wave * 16 + p * 8;                                             \
      gload16(&(Aptr)[(size_t)(m0 + r0 + arow) * (lda) + (kb) + acol],        \
              &Als[buf][r0 * BK]);                                            \
    }                                                                         \
    _Pragma("unroll") for (int p = 0; p < 4; ++p) {                           \
      int r0 = wave * 32 + p * 8;                                             \
      gload16(&(Bptr)[(size_t)(n0 + r0 + arow) * (ldb) + (kb) + acol],        \
              &Bls[buf][r0 * BK]);                                            \
    }                                                                         \
  }

#define GEMM64_COMP(buf)                                                      \
  {                                                                           \
    const u16* Ab = &Als[buf][0];                                             \
    const u16* Bb = &Bls[buf][0];                                             \
    _Pragma("unroll") for (int kk8 = 0; kk8 < 8; kk8 += 4) {                  \
      int cg = (((kk8 + quad) & 7) ^ (l15 & 7)) << 3;                         \
      short8 af[2], bfr[4];                                                   \
      _Pragma("unroll") for (int i = 0; i < 2; ++i)                           \
          af[i] = *(const short8*)&Ab[(wr + i * 16 + l15) * BK + cg];         \
      _Pragma("unroll") for (int j = 0; j < 4; ++j)                           \
          bfr[j] = *(const short8*)&Bb[(wc + j * 16 + l15) * BK + cg];        \
      _Pragma("unroll") for (int i = 0; i < 2; ++i)                           \
      _Pragma("unroll") for (int j = 0; j < 4; ++j)                           \
          acc[i][j] = __builtin_amdgcn_mfma_f32_16x16x32_bf16(                \
              af[i], bfr[j], acc[i][j], 0, 0, 0);                             \
    }                                                                         \
  }

#define GEMM64_KLOOP(Aptr, lda, Bptr, ldb, KEND)                              \
  _Pragma("unroll 1") for (int kb = 0; kb < (KEND); kb += 2 * BK) {           \
    bool two = (kb + BK < (KEND));                                            \
    __syncthreads();                                                          \
    GEMM64_STAGE(0, Aptr, lda, Bptr, ldb, kb);                                \
    if (two) GEMM64_STAGE(1, Aptr, lda, Bptr, ldb, kb + BK);                  \
    __syncthreads();                                                          \
    GEMM64_COMP(0);                                                           \
    if (two) GEMM64_COMP(1);                                                  \
  }

// ---- scores tile body (decode + GEMM + exp/causal epilogue) ----
#define SCORES_TILE(id_)                                                      \
  {                                                                           \
    int xcd = (id_) & 7;                                                      \
    int b = xcd & 3, h = xcd >> 2;                                            \
    int t = (id_) >> 3;                                                       \
    int m = (int)((sqrtf(8.f * (float)t + 1.f) - 1.f) * 0.5f);                \
    while ((m + 1) * (m + 2) / 2 <= t) ++m;                                   \
    while (m * (m + 1) / 2 > t) --m;                                          \
    int bj = t - m * (m + 1) / 2;                                             \
    int bi = 2 * m + h;                                                       \
    int m0 = bi * 64, n0 = bj * 128;                                          \
    const u16* A = WQ + (size_t)b * S_LEN * D_DIM;                            \
    const u16* Bp = WKV + (size_t)b * S_LEN * D_DIM;                          \
    floatx4 acc[2][4];                                                        \
    _Pragma("unroll") for (int i = 0; i < 2; ++i)                             \
    _Pragma("unroll") for (int j = 0; j < 4; ++j)                             \
        acc[i][j] = (floatx4){0.f, 0.f, 0.f, 0.f};                            \
    GEMM64_KLOOP(A, D_DIM, Bp, D_DIM, D_DIM);                                 \
    u16* Pb = Pp + (size_t)b * S_LEN * S_LEN;                                 \
    float part[2][4];                                                         \
    _Pragma("unroll") for (int i = 0; i < 2; ++i)                             \
    _Pragma("unroll") for (int r = 0; r < 4; ++r) part[i][r] = 0.f;           \
    _Pragma("unroll") for (int i = 0; i < 2; ++i)                             \
    _Pragma("unroll") for (int j = 0; j < 4; ++j) {                           \
      int col = n0 + wc + j * 16 + l15;                                       \
      _Pragma("unroll") for (int r = 0; r < 4; ++r) {                         \
        int row = m0 + wr + i * 16 + quad * 4 + r;                            \
        float p = (col > row) ? 0.f : __expf(acc[i][j][r] * 0.03125f);        \
        Pb[(size_t)row * S_LEN + col] = f2b(p);                               \
        part[i][r] += p;                                                      \
      }                                                                       \
    }                                                                         \
    _Pragma("unroll") for (int i = 0; i < 2; ++i)                             \
    _Pragma("unroll") for (int r = 0; r < 4; ++r) {                           \
      float v = part[i][r];                                                   \
      _Pragma("unroll") for (int off = 1; off < 16; off <<= 1)                \
          v += __shfl_xor(v, off, 64);                                        \
      part[i][r] = v;                                                         \
    }                                                                         \
    if (l15 == 0) {                                                           \
      _Pragma("unroll") for (int i = 0; i < 2; ++i)                           \
      _Pragma("unroll") for (int r = 0; r < 4; ++r)                           \
          atomicAdd(&rowsum[b * S_LEN + m0 + wr + i * 16 + quad * 4 + r],     \
                    part[i][r]);                                              \
    }                                                                         \
  }

// ---- pv tile body (decode + GEMM + divide epilogue) ----
#define PV_TILE(id_)                                                          \
  {                                                                           \
    int xcd = (id_) & 7;                                                      \
    int b = xcd & 3, h = xcd >> 2;                                            \
    int r_ = (id_) >> 3;                                                      \
    int mh = 15 - (r_ >> 3);                                                  \
    int bi = 2 * mh + h;                                                      \
    int bj = r_ & 7;                                                          \
    int m0 = bi * 64, n0 = bj * 128;                                          \
    int kend = (bi + 1) * 64;                                                 \
    const u16* A = Pp + (size_t)b * S_LEN * S_LEN;                            \
    const u16* Bp = WKVt + (size_t)b * (size_t)D_DIM * S_LEN;                 \
    floatx4 acc[2][4];                                                        \
    _Pragma("unroll") for (int i = 0; i < 2; ++i)                             \
    _Pragma("unroll") for (int j = 0; j < 4; ++j)                             \
        acc[i][j] = (floatx4){0.f, 0.f, 0.f, 0.f};                            \
    GEMM64_KLOOP(A, S_LEN, Bp, S_LEN, kend);                                  \
    const float* rs = rowsum + b * S_LEN;                                     \
    float* Co = out + (size_t)b * S_LEN * D_DIM;                              \
    _Pragma("unroll") for (int i = 0; i < 2; ++i)                             \
    _Pragma("unroll") for (int r = 0; r < 4; ++r) {                           \
      int row = m0 + wr + i * 16 + quad * 4 + r;                              \
      float inv = 1.0f / rs[row];                                             \
      _Pragma("unroll") for (int j = 0; j < 4; ++j)                           \
          Co[(size_t)row * D_DIM + (n0 + wc + j * 16 + l15)] =                \
              acc[i][j][r] * inv;                                             \
    }                                                                         \
  }

// Fallback standalone kernels (proven r8 structure).
__global__ __launch_bounds__(256)
void gemm_scores(const u16* __restrict__ WQ, const u16* __restrict__ WKV,
                 u16* __restrict__ Pp, float* __restrict__ rowsum) {
  GEMM64_PROLOG();
  SCORES_TILE(blockIdx.x);
}

__global__ __launch_bounds__(256)
void gemm_pv(const u16* __restrict__ Pp, const u16* __restrict__ WKVt,
             const float* __restrict__ rowsum, float* __restrict__ out) {
  GEMM64_PROLOG();
  PV_TILE(blockIdx.x);
}

// Cooperative fused scores+pv. Grid 768 = 3 blocks/CU (48KB LDS;
// launch_bounds(256,3) guarantees 3 waves/SIMD residency for the capacity
// check). Block b: scores tiles {b, b+768} -> grid.sync -> pv {b, b+768}.
// ONE fence per block at the phase boundary (r11's failure was per-tile).
__global__ __launch_bounds__(256, 3)
void gemm_sp(const u16* __restrict__ WQ, const u16* __restrict__ WKV,
             const u16* __restrict__ WKVt, u16* __restrict__ Pp,
             float* __restrict__ rowsum, float* __restrict__ out) {
  GEMM64_PROLOG();
  (void)acc;  // per-tile accs are declared inside the tile bodies
#pragma unroll 1
  for (int s = 0; s < 2; ++s) {
    int id = (int)blockIdx.x + s * 768;
    if (id >= 1088) break;
    SCORES_TILE(id);
  }
  __threadfence();  // release Pp stores + rowsum atomics
  cooperative_groups::this_grid().sync();
  __threadfence();  // acquire: one invalidation per block, at the boundary
#pragma unroll 1
  for (int s = 0; s < 2; ++s) {
    int id = (int)blockIdx.x + s * 768;
    if (id >= 1024) break;
    PV_TILE(id);
  }
}

extern "C" void kernel_launch(void* const* d_in, const int* in_sizes, int n_in,
                              void* d_out, int out_size, void* d_ws, size_t ws_size,
                              hipStream_t stream) {
  const float* q = (const float*)d_in[0];
  const float* Wq = (const float*)d_in[1];
  // d_in[2] (Wk) unused; d_in[4] (mask) unused.
  const float* Wv = (const float*)d_in[3];
  char* ws = (char*)d_ws;
  const size_t MB = 1024 * 1024;
  u16* Wqt = (u16*)(ws);
  u16* Wvt = (u16*)(ws + 2 * MB);
  u16* qb16 = (u16*)(ws + 4 * MB);
  u16* Pp = (u16*)(ws);                   // overlays the above after proj
  u16* WQ = (u16*)(ws + 32 * MB);
  u16* WKV = (u16*)(ws + 48 * MB);
  u16* WKVt = (u16*)(ws + 64 * MB);
  float* rowsum = (float*)(ws + 80 * MB);
  float* outp = (float*)d_out;

  prep<<<4608, 256, 0, stream>>>(q, qb16, Wq, Wqt, Wv, Wvt, rowsum);
  gemm_proj<<<256, 512, 0, stream>>>(qb16, Wqt, Wvt, WQ, WKV, WKVt);

  const u16* cWQ = WQ;
  const u16* cWKV = WKV;
  const u16* cWKVt = WKVt;
  void* args[] = {(void*)&cWQ, (void*)&cWKV, (void*)&cWKVt,
                  (void*)&Pp,  (void*)&rowsum, (void*)&outp};
  hipError_t e = hipLaunchCooperativeKernel((const void*)gemm_sp, dim3(768),
                                            dim3(256), args, 0, stream);
  if (e != hipSuccess) {
    // Fallback: proven r8 separate launches.
    gemm_scores<<<1088, 256, 0, stream>>>(WQ, WKV, Pp, rowsum);
    gemm_pv<<<1024, 256, 0, stream>>>(Pp, WKVt, rowsum, outp);
  }
}

// Round 14
// 198.486 us; speedup vs baseline: 2.3688x; 2.3688x over previous
//
#include <hip/hip_runtime.h>

// Attention_34187939676863 on MI355X (gfx950). fp32 I/O, bf16 MFMA internally.
// B=4, S=2048, D=1024.  Wk unused (reference bug: Wv used for both K and V),
// mask unused (causal structure implemented directly).
//
//   prep  : qb16 = bf16(q); Wqt/Wvt transposes; rowsum = 0   [one kernel]
//   WQ    = qb16 @ Wq,  WKV = qb16 @ Wv      [256x256 8-phase bt-GEMM, XCD-pinned
//                                             m-stripes; z=1 epilogue also emits WKVt]
//   P'    = exp(WQ @ WKV^T / 32) causal bf16 [64x128 bt-GEMM, 2 K-tiles/superstep]
//   rowsum= sum_k P'                          [fused epilogue atomics]
//   out   = (P' @ WKV) / rowsum  fp32        [64x128 bt-GEMM, 2 K-tiles/superstep]
//
// Round-19 FINAL: revert to the r8/r12 configuration (three-run band:
// 198.7 / 204.8 / 202.7 us). Both fusion mechanisms for the ~60us
// inter-dispatch gap failed: r11 (persistent queue + per-tile fences) ->
// 280MB FETCH, 522us; r13 (cooperative + one grid.sync) -> coherence fine
// (63MB FETCH) but static 2-round work map idles 58% of CUs in round 2 and
// grid.sync waits on the slowest round -> 301us. Lesson: on this workload,
// kernel boundaries do scheduler backfill + bulk coherence more efficiently
// than software re-implementations at HIP level.
// Session history: 216.8 -> ~200. proj 61 -> 43.5 (256^2 8-phase counted-
// vmcnt, launch_bounds(512,2)); scores/pv 43 -> ~35-class (2-tile superstep,
// 16 -> 8 drains); prep fusion (6 -> 4 dispatches). Probed and rejected:
// 128^2 tiles (granularity), dbuf/ring/counted-vmcnt on 4-wave kernels
// (latency not pipeline-hideable at low occupancy), 64x64 tiles (intensity),
// persistent fusion (coherence), cooperative fusion (static-map imbalance).
//
// Workspace (needs ws_size >= 81 MB):
//   [0,2)MB Wqt | [2,4) Wvt | [4,20) qb16   <- dead after proj
//   [0,32) Pp bf16 [B][S][S] (overlays the above)
//   [32,48) WQ | [48,64) WKV | [64,80) WKVt | [80MB,+32KB) rowsum fp32

typedef unsigned short u16;
typedef short short8 __attribute__((ext_vector_type(8)));
typedef float floatx4 __attribute__((ext_vector_type(4)));

#define S_LEN 2048
#define D_DIM 1024
#define BK 64

__device__ inline u16 f2b(float f) {
  unsigned u = __float_as_uint(f);
  return (u16)((u + 0x7fffu + ((u >> 16) & 1u)) >> 16);
}

// async global->LDS, 16B/lane; LDS dest = wave-uniform base + lane*16
__device__ __forceinline__ void gload16(const u16* g, u16* l) {
  __builtin_amdgcn_global_load_lds(
      (const __attribute__((address_space(1))) void*)g,
      (__attribute__((address_space(3))) void*)l, 16, 0, 0);
}

// prep: grid 4608 x 256.
//   id <  4096 : cvt q -> qb16 (8 elems/thread); ids 0..3 also zero rowsum
//   id >= 4096 : 64x64 f32->bf16 transpose tiles of Wq->Wqt (z=0) / Wv->Wvt (z=1)
__global__ __launch_bounds__(256)
void prep(const float* __restrict__ q, u16* __restrict__ qb16,
          const float* __restrict__ Wq, u16* __restrict__ Wqt,
          const float* __restrict__ Wv, u16* __restrict__ Wvt,
          float* __restrict__ rowsum) {
  int id = blockIdx.x, tid = threadIdx.x;
  if (id < 4096) {
    if (id < 4) {
      int o = id * 2048 + tid * 8;
      float4 zz = {0.f, 0.f, 0.f, 0.f};
      *(float4*)&rowsum[o] = zz;
      *(float4*)&rowsum[o + 4] = zz;
    }
    size_t idx = ((size_t)id * 256 + tid) * 8;
    float4 a0 = *(const float4*)&q[idx];
    float4 a1 = *(const float4*)&q[idx + 4];
    short8 v;
    v[0] = (short)f2b(a0.x); v[1] = (short)f2b(a0.y);
    v[2] = (short)f2b(a0.z); v[3] = (short)f2b(a0.w);
    v[4] = (short)f2b(a1.x); v[5] = (short)f2b(a1.y);
    v[6] = (short)f2b(a1.z); v[7] = (short)f2b(a1.w);
    *(short8*)&qb16[idx] = v;
    return;
  }
  __shared__ u16 tile[64][65];
  int id2 = id - 4096;               // 0..511
  int z = id2 >> 8;                  // matrix select
  int idx4 = id2 & 255;
  int c0 = (idx4 & 15) * 64, r0 = (idx4 >> 4) * 64;
  const float* src = z ? Wv : Wq;
  u16* dst = z ? Wvt : Wqt;
  int tx = tid & 63, ty = tid >> 6;
#pragma unroll
  for (int i = 0; i < 16; ++i)
    tile[i * 4 + ty][tx] =
        f2b(src[(size_t)(r0 + i * 4 + ty) * 1024 + (c0 + tx)]);
  __syncthreads();
#pragma unroll
  for (int i = 0; i < 16; ++i)
    dst[(size_t)(c0 + i * 4 + ty) * 1024 + (r0 + tx)] = tile[tx][i * 4 + ty];
}

// Projections: WQ = qb16 @ Wqt^T (z=0), WKV = qb16 @ Wvt^T (z=1; also WKVt).
// 256x256 tile, 8 waves (2m x 4n), 8-phase double-buffered K-loop.
// Grid 256 = 8 XCDs x (4 m-stripes x 8 n-tiles): 1 block/CU exactly.
__global__ __launch_bounds__(512, 2)
void gemm_proj(const u16* __restrict__ A, const u16* __restrict__ B0,
               const u16* __restrict__ B1, u16* __restrict__ C0,
               u16* __restrict__ C1, u16* __restrict__ WKVt) {
  __shared__ __align__(16) u16 lds[65536];  // 128 KiB

  int id = blockIdx.x;
  int xcd = id & 7, i5 = id >> 3;
  int m_idx = xcd * 4 + (i5 & 3);  // XCD owns 4 m-stripes (2MB of A in L2)
  int n_idx = i5 >> 2;             // 0..7
  int z = n_idx >> 2;
  int n0 = (n_idx & 3) * 256;
  int m0 = m_idx * 256;
  const u16* Bp = z ? B1 : B0;
  u16* Cp = z ? C1 : C0;

  int tid = threadIdx.x;
  int wv = tid >> 6, lane = tid & 63, quad = lane >> 4, l15 = lane & 15;
  int wm = wv >> 2, wn = wv & 3;  // wave -> (m-half, n-quarter)

  int off_g[2];
#pragma unroll
  for (int l = 0; l < 2; ++l) {
    int chunk = (wv * 2 + l) * 64 + lane;
    int r = chunk >> 3, cs = chunk & 7;
    off_g[l] = r * 1024 + (cs ^ (r & 7)) * 8;
  }
  const u16* As0 = A + (size_t)m0 * 1024;
  const u16* As1 = A + (size_t)(m0 + 128) * 1024;
  const u16* Bs0 = Bp + (size_t)n0 * 1024;
  const u16* Bs1 = Bp + (size_t)(n0 + 128) * 1024;

#define PSTAGE(src, reg)                                                     \
  {                                                                          \
    _Pragma("unroll") for (int l = 0; l < 2; ++l)                            \
        gload16((src) + off_g[l], &lds[(reg) * 8192 + (wv * 2 + l) * 512]);  \
  }

  int aoff[2], boff[2];
#pragma unroll
  for (int kk = 0; kk < 2; ++kk) {
    int c = ((kk * 4 + quad) ^ (l15 & 7)) * 8;
    aoff[kk] = l15 * 64 + c;
    boff[kk] = ((wn & 1) * 64 + l15) * 64 + c;
  }
  const u16* A0p = &lds[(0 + wm) * 8192];         // buf0 A-half of this wave
  const u16* A1p = &lds[(4 + wm) * 8192];         // buf1 A-half
  const u16* B0p = &lds[(2 + (wn >> 1)) * 8192];  // buf0 B-half
  const u16* B1p = &lds[(6 + (wn >> 1)) * 8192];  // buf1 B-half

  floatx4 acc[8][4];
#pragma unroll
  for (int i = 0; i < 8; ++i)
#pragma unroll
    for (int j = 0; j < 4; ++j) acc[i][j] = (floatx4){0.f, 0.f, 0.f, 0.f};

#define BARp() __builtin_amdgcn_s_barrier()
#define WLG() asm volatile("s_waitcnt lgkmcnt(0)" ::: "memory")
#define WVM(n) asm volatile("s_waitcnt vmcnt(" #n ")" ::: "memory")

#define RDA(dst, base, fb)                                                 \
  _Pragma("unroll") for (int f = 0; f < 4; ++f)                            \
  _Pragma("unroll") for (int kk = 0; kk < 2; ++kk)                         \
      dst[f][kk] = *(const short8*)&(base)[((fb) + f) * 1024 + aoff[kk]];
#define RDB(dst, base, fb)                                                 \
  _Pragma("unroll") for (int f = 0; f < 2; ++f)                            \
  _Pragma("unroll") for (int kk = 0; kk < 2; ++kk)                         \
      dst[f][kk] = *(const short8*)&(base)[((fb) + f) * 1024 + boff[kk]];
#define MMQ(mh, nh, afq, bfq)                                              \
  __builtin_amdgcn_s_setprio(1);                                           \
  _Pragma("unroll") for (int f = 0; f < 4; ++f)                            \
  _Pragma("unroll") for (int g2 = 0; g2 < 2; ++g2)                         \
  _Pragma("unroll") for (int kk = 0; kk < 2; ++kk)                         \
      acc[(mh) * 4 + f][(nh) * 2 + g2] =                                   \
          __builtin_amdgcn_mfma_f32_16x16x32_bf16(                         \
              afq[f][kk], bfq[g2][kk], acc[(mh) * 4 + f][(nh) * 2 + g2],   \
              0, 0, 0);                                                    \
  __builtin_amdgcn_s_setprio(0);

  // Prologue: stage kt0 (regions 0-3) + kt1 (regions 4-7); wait kt0 landed.
  PSTAGE(As0, 0); PSTAGE(As1, 1); PSTAGE(Bs0, 2); PSTAGE(Bs1, 3);
  PSTAGE(As0 + 64, 4); PSTAGE(As1 + 64, 5); PSTAGE(Bs0 + 64, 6);
  PSTAGE(Bs1 + 64, 7);
  WVM(8);
  BARp();

#pragma unroll 1
  for (int it = 0; it < 8; ++it) {
    int kb2 = it * 128 + 128, kb3 = it * 128 + 192;  // kt+2 / kt+3 K-bases
    short8 af[4][2], bf0[2][2], bf1[2][2];
    // ---- K-tile 2it (buf0), phases q0..q3 ----
    RDA(af, A0p, 0); RDB(bf0, B0p, 0);
    BARp(); WLG();
    MMQ(0, 0, af, bf0);
    BARp();
    RDB(bf1, B0p, 2);
    BARp(); WLG();
    MMQ(0, 1, af, bf1);
    BARp();
    RDA(af, A0p, 4);
    if (it < 7) PSTAGE(Bs0 + kb2, 2);
    BARp(); WLG();
    MMQ(1, 1, af, bf1);
    BARp();
    if (it < 7) { PSTAGE(Bs1 + kb2, 3); PSTAGE(As0 + kb2, 0); }
    BARp();
    MMQ(1, 0, af, bf0);
    if (it < 7) { WVM(6); } else { WVM(0); }  // buf1 K-tile landed
    BARp();
    // ---- K-tile 2it+1 (buf1), phases q4..q7 ----
    RDA(af, A1p, 0); RDB(bf0, B1p, 0);
    if (it < 7) PSTAGE(As1 + kb2, 1);
    BARp(); WLG();
    MMQ(0, 0, af, bf0);
    BARp();
    RDB(bf1, B1p, 2);
    BARp(); WLG();
    MMQ(0, 1, af, bf1);
    BARp();
    RDA(af, A1p, 4);
    if (it < 7) PSTAGE(Bs0 + kb3, 6);
    BARp(); WLG();
    MMQ(1, 1, af, bf1);
    BARp();
    if (it < 7) {
      PSTAGE(Bs1 + kb3, 7); PSTAGE(As0 + kb3, 4); PSTAGE(As1 + kb3, 5);
    }
    BARp();
    MMQ(1, 0, af, bf0);
    if (it < 7) WVM(8);  // next buf0 K-tile landed
    BARp();
  }

  asm volatile("s_waitcnt vmcnt(0) lgkmcnt(0)" ::: "memory");
  // C write. C/D layout: col=lane&15, row=quad*4+reg  [m89-verified]
#pragma unroll
  for (int mf = 0; mf < 8; ++mf)
#pragma unroll
    for (int nf = 0; nf < 4; ++nf)
#pragma unroll
      for (int r = 0; r < 4; ++r)
        Cp[(size_t)(m0 + wm * 128 + mf * 16 + quad * 4 + r) * D_DIM +
           (n0 + wn * 64 + nf * 16 + l15)] = f2b(acc[mf][nf][r]);

  if (z) {
    // Fused WKV^T: acc -> LDS transposed (two 128-col passes) -> 16B stores.
    int b = m0 >> 11, srow = m0 & 2047;
    u16* Wt = WKVt + (size_t)b * D_DIM * S_LEN;
#pragma unroll
    for (int ph = 0; ph < 2; ++ph) {
      BARp();  // LDS reusable / previous pass reads done
      if ((wn >> 1) == ph) {
#pragma unroll
        for (int mf = 0; mf < 8; ++mf)
#pragma unroll
          for (int nf = 0; nf < 4; ++nf)
#pragma unroll
            for (int r = 0; r < 4; ++r)
              lds[((wn & 1) * 64 + nf * 16 + l15) * 272 +
                  (wm * 128 + mf * 16 + quad * 4 + r)] = f2b(acc[mf][nf][r]);
      }
      BARp();
#pragma unroll
      for (int rr = 0; rr < 8; ++rr) {
        int idx = rr * 512 + tid;  // 0..4095: (d-local, s-chunk)
        int dl = idx >> 5, sc = idx & 31;
        *(short8*)&Wt[(size_t)(n0 + ph * 128 + dl) * S_LEN + srow + sc * 8] =
            *(const short8*)&lds[dl * 272 + sc * 8];
      }
    }
  }
}

// ---- 64x128-tile bt-GEMM core, 2 K-tiles per superstep (scores/pv) ----
// Halves barrier-pair count 16 -> 8: each superstep stages BK=64 tiles
// kb and kb+64 into two independent single-buffers, one __syncthreads pair,
// then computes them in order (bit-identical accumulation to r4).
#define GEMM64_PROLOG()                                                       \
  __shared__ __align__(16) u16 Als[2][64 * BK];                               \
  __shared__ __align__(16) u16 Bls[2][128 * BK];                              \
  int tid = threadIdx.x;                                                      \
  int wave = tid >> 6, lane = tid & 63, quad = lane >> 4, l15 = lane & 15;    \
  int wr = (wave >> 1) * 32, wc = (wave & 1) * 64;                            \
  int arow = lane >> 3;                                                       \
  int acol = ((lane & 7) ^ (arow & 7)) << 3;                                  \
  floatx4 acc[2][4];                                                          \
  _Pragma("unroll") for (int i = 0; i < 2; ++i)                               \
  _Pragma("unroll") for (int j = 0; j < 4; ++j)                               \
      acc[i][j] = (floatx4){0.f, 0.f, 0.f, 0.f};

#define GEMM64_STAGE(buf, Aptr, lda, Bptr, ldb, kb)                           \
  {                                                                           \
    _Pragma("unroll") for (int p = 0; p < 2; ++p) {                           \
      int r0 = wave * 16 + p * 8;                                             \
      gload16(&(Aptr)[(size_t)(m0 + r0 + arow) * (lda) + (kb) + acol],        \
              &Als[buf][r0 * BK]);                                            \
    }                                                                         \
    _Pragma("unroll") for (int p = 0; p < 4; ++p) {                           \
      int r0 = wave * 32 + p * 8;                                             \
      gload16(&(Bptr)[(size_t)(n0 + r0 + arow) * (ldb) + (kb) + acol],        \
              &Bls[buf][r0 * BK]);                                            \
    }                                                                         \
  }

#define GEMM64_COMP(buf)                                                      \
  {                                                                           \
    const u16* Ab = &Als[buf][0];                                             \
    const u16* Bb = &Bls[buf][0];                                             \
    _Pragma("unroll") for (int kk8 = 0; kk8 < 8; kk8 += 4) {                  \
      int cg = (((kk8 + quad) & 7) ^ (l15 & 7)) << 3;                         \
      short8 af[2], bfr[4];                                                   \
      _Pragma("unroll") for (int i = 0; i < 2; ++i)                           \
          af[i] = *(const short8*)&Ab[(wr + i * 16 + l15) * BK + cg];         \
      _Pragma("unroll") for (int j = 0; j < 4; ++j)                           \
          bfr[j] = *(const short8*)&Bb[(wc + j * 16 + l15) * BK + cg];        \
      _Pragma("unroll") for (int i = 0; i < 2; ++i)                           \
      _Pragma("unroll") for (int j = 0; j < 4; ++j)                           \
          acc[i][j] = __builtin_amdgcn_mfma_f32_16x16x32_bf16(                \
              af[i], bfr[j], acc[i][j], 0, 0, 0);                             \
    }                                                                         \
  }

#define GEMM64_KLOOP(Aptr, lda, Bptr, ldb, KEND)                              \
  _Pragma("unroll 1") for (int kb = 0; kb < (KEND); kb += 2 * BK) {           \
    bool two = (kb + BK < (KEND));                                            \
    __syncthreads();                                                          \
    GEMM64_STAGE(0, Aptr, lda, Bptr, ldb, kb);                                \
    if (two) GEMM64_STAGE(1, Aptr, lda, Bptr, ldb, kb + BK);                  \
    __syncthreads();                                                          \
    GEMM64_COMP(0);                                                           \
    if (two) GEMM64_COMP(1);                                                  \
  }

// Causal scores: P' = exp(WQ @ WKV^T / 32) masked; rowsum += partials.
// Grid 1088 = 8 XCD slots x 136 triangular tiles. XCD -> (batch, bi-parity):
// each XCD touches only alternating 64-row stripes of WQ (2MB A footprint).
__global__ __launch_bounds__(256)
void gemm_scores(const u16* __restrict__ WQ, const u16* __restrict__ WKV,
                 u16* __restrict__ Pp, float* __restrict__ rowsum) {
  int id = blockIdx.x;
  int xcd = id & 7;
  int b = xcd & 3, h = xcd >> 2;
  int t = id >> 3;  // 0..135 triangular index (m,bj), bj<=m, m=0..15
  int m = (int)((sqrtf(8.f * (float)t + 1.f) - 1.f) * 0.5f);
  while ((m + 1) * (m + 2) / 2 <= t) ++m;
  while (m * (m + 1) / 2 > t) --m;
  int bj = t - m * (m + 1) / 2;
  int bi = 2 * m + h;
  int m0 = bi * 64, n0 = bj * 128;
  const u16* A = WQ + (size_t)b * S_LEN * D_DIM;
  const u16* Bp = WKV + (size_t)b * S_LEN * D_DIM;
  GEMM64_PROLOG();
  GEMM64_KLOOP(A, D_DIM, Bp, D_DIM, D_DIM);
  u16* Pb = Pp + (size_t)b * S_LEN * S_LEN;
  float part[2][4];
#pragma unroll
  for (int i = 0; i < 2; ++i)
#pragma unroll
    for (int r = 0; r < 4; ++r) part[i][r] = 0.f;
#pragma unroll
  for (int i = 0; i < 2; ++i)
#pragma unroll
    for (int j = 0; j < 4; ++j) {
      int col = n0 + wc + j * 16 + l15;
#pragma unroll
      for (int r = 0; r < 4; ++r) {
        int row = m0 + wr + i * 16 + quad * 4 + r;
        float p = (col > row) ? 0.f : __expf(acc[i][j][r] * 0.03125f);
        Pb[(size_t)row * S_LEN + col] = f2b(p);
        part[i][r] += p;
      }
    }
#pragma unroll
  for (int i = 0; i < 2; ++i)
#pragma unroll
    for (int r = 0; r < 4; ++r) {
      float v = part[i][r];
#pragma unroll
      for (int off = 1; off < 16; off <<= 1) v += __shfl_xor(v, off, 64);
      part[i][r] = v;
    }
  if (l15 == 0) {
#pragma unroll
    for (int i = 0; i < 2; ++i)
#pragma unroll
      for (int r = 0; r < 4; ++r)
        atomicAdd(&rowsum[b * S_LEN + m0 + wr + i * 16 + quad * 4 + r],
                  part[i][r]);
  }
}

// out = (P' @ WKV) / rowsum, causal K. Grid 1024 = 8 XCD slots x 128 tiles;
// XCD -> (batch, bi-parity); longest-K (largest bi) first within each slot.
// Upper-tri Pp entries within [0,kend) are exact 0 -> safe to include.
__global__ __launch_bounds__(256)
void gemm_pv(const u16* __restrict__ Pp, const u16* __restrict__ WKVt,
             const float* __restrict__ rowsum, float* __restrict__ out) {
  int id = blockIdx.x;
  int xcd = id & 7;
  int b = xcd & 3, h = xcd >> 2;
  int r_ = id >> 3;  // 0..127
  int mh = 15 - (r_ >> 3);
  int bi = 2 * mh + h;
  int bj = r_ & 7;
  int m0 = bi * 64, n0 = bj * 128;
  int kend = (bi + 1) * 64;
  const u16* A = Pp + (size_t)b * S_LEN * S_LEN;
  const u16* Bp = WKVt + (size_t)b * (size_t)D_DIM * S_LEN;
  GEMM64_PROLOG();
  GEMM64_KLOOP(A, S_LEN, Bp, S_LEN, kend);
  const float* rs = rowsum + b * S_LEN;
  float* Co = out + (size_t)b * S_LEN * D_DIM;
#pragma unroll
  for (int i = 0; i < 2; ++i)
#pragma unroll
    for (int r = 0; r < 4; ++r) {
      int row = m0 + wr + i * 16 + quad * 4 + r;
      float inv = 1.0f / rs[row];
#pragma unroll
      for (int j = 0; j < 4; ++j)
        Co[(size_t)row * D_DIM + (n0 + wc + j * 16 + l15)] =
            acc[i][j][r] * inv;
    }
}

extern "C" void kernel_launch(void* const* d_in, const int* in_sizes, int n_in,
                              void* d_out, int out_size, void* d_ws, size_t ws_size,
                              hipStream_t stream) {
  const float* q = (const float*)d_in[0];
  const float* Wq = (const float*)d_in[1];
  // d_in[2] (Wk) unused; d_in[4] (mask) unused.
  const float* Wv = (const float*)d_in[3];
  char* ws = (char*)d_ws;
  const size_t MB = 1024 * 1024;
  u16* Wqt = (u16*)(ws);
  u16* Wvt = (u16*)(ws + 2 * MB);
  u16* qb16 = (u16*)(ws + 4 * MB);
  u16* Pp = (u16*)(ws);                   // overlays the above after proj
  u16* WQ = (u16*)(ws + 32 * MB);
  u16* WKV = (u16*)(ws + 48 * MB);
  u16* WKVt = (u16*)(ws + 64 * MB);
  float* rowsum = (float*)(ws + 80 * MB);

  prep<<<4608, 256, 0, stream>>>(q, qb16, Wq, Wqt, Wv, Wvt, rowsum);
  gemm_proj<<<256, 512, 0, stream>>>(qb16, Wqt, Wvt, WQ, WKV, WKVt);
  gemm_scores<<<1088, 256, 0, stream>>>(WQ, WKV, Pp, rowsum);
  gemm_pv<<<1024, 256, 0, stream>>>(Pp, WKVt, rowsum, (float*)d_out);
}